// Round 7
// baseline (5296.738 us; speedup 1.0000x reference)
//
#include <hip/hip_runtime.h>
#include <hip/hip_bf16.h>

// GaussianLSTM: x(4,512,256) -> 2-layer LSTM(H=256) -> Gaussian head.
// Outputs concat: sample (524288) | mu (524288) | std_full (134217728) f32.
//
// Round 7: 3-CU dataflow pipeline, intra-CU recurrence, one-way streams.
//   WG0 (L0): W_hh0 fully resident (12 reg tiles/wave + 4 LDS tiles/wave).
//     Recurrence h0(t): h in LDS, one __syncthreads per step. Publishes h0
//     as tagged u64 words (agent atomics, fire-and-forget).
//   WG1 (streamer): W_ih1 resident same way. Polls h0 stream (constant skew,
//     OFF the serial chain), computes xw1(t)=bias1+W_ih1@h0(t), publishes
//     tagged words.
//   WG2 (L1): W_hh1 resident. Own recurrence intra-CU; consumes xw1 stream
//     (poll = batched 16 loads + validate -> one latency per attempt).
//   Protocol correctness never depends on placement/caches: agent-scope
//   atomics only (round-3-proven). Latency only affects pipeline skew.
//   Replay-safe: pubs live in std_full region (finalize rewrites each call;
//   f32/0xAA bit patterns never equal tags 1..512).

#define HD 256
#define SEQ 512

typedef __attribute__((ext_vector_type(8))) short short8;
typedef __attribute__((ext_vector_type(4))) float f32x4;
using u16 = unsigned short;
using u32 = unsigned int;
using u64 = unsigned long long;

#define MFMA16(a, bm, c) __builtin_amdgcn_mfma_f32_16x16x32_bf16((a), (bm), (c), 0, 0, 0)

__device__ inline u16 f2bf(float x) {
  u32 u = __float_as_uint(x);
  u32 r = (u + 0x7FFFu + ((u >> 16) & 1u)) >> 16;
  return (u16)r;
}
__device__ inline u32 pk2(float a, float b) {
  return (u32)f2bf(a) | ((u32)f2bf(b) << 16);
}
__device__ inline float fast_sigmoid(float z) { return 1.0f / (1.0f + __expf(-z)); }
__device__ inline float fast_tanh(float z) { return 1.0f - 2.0f / (1.0f + __expf(2.0f * z)); }

__device__ __forceinline__ u64 aload(const u64* p) {
  return __hip_atomic_load(p, __ATOMIC_RELAXED, __HIP_MEMORY_SCOPE_AGENT);
}
__device__ __forceinline__ void astore(u64* p, u64 v) {
  __hip_atomic_store(p, v, __ATOMIC_RELAXED, __HIP_MEMORY_SCOPE_AGENT);
}

// ---------------- prep: pack W_hh0/W_ih1/W_hh1 into bf16 MFMA-frag layout ----
// pk[mat][ti][kk][ll][j]: ti = w*16+q*4+m; row = m*256+w*64+q*16+(ll&15);
// k = kk*32+(ll>>4)*8+j.  (Round-4-verified mapping.)
__global__ __launch_bounds__(256) void prep_pack(
    const float* __restrict__ whh0, const float* __restrict__ wih1,
    const float* __restrict__ whh1, const float* __restrict__ bi1,
    const float* __restrict__ bh1, u16* __restrict__ pk,
    float* __restrict__ bias1s) {
  const int idx = blockIdx.x * 256 + threadIdx.x;
  if (idx < 786432) {
    const int mat = idx >> 18;
    const int e = idx & 262143;
    const int ti = e >> 12, r2 = e & 4095;
    const int kk = r2 >> 9, ll = (r2 >> 3) & 63, j = r2 & 7;
    const int w = ti >> 4, p = (ti >> 2) & 3, m = ti & 3;
    const int row = m * 256 + w * 64 + p * 16 + (ll & 15);
    const int k = kk * 32 + (ll >> 4) * 8 + j;
    const float* src = (mat == 0) ? whh0 : (mat == 1) ? wih1 : whh1;
    pk[idx] = f2bf(src[(size_t)row * 256 + k]);
  } else {
    const int i = idx - 786432;
    if (i < 1024) bias1s[i] = bi1[i] + bh1[i];
  }
}

// ------------------------------------------------- xw = in @ w^T + (ba+bb)
__global__ __launch_bounds__(256) void xw_gemm(
    const float* __restrict__ xin, const float* __restrict__ w,
    const float* __restrict__ ba, const float* __restrict__ bb,
    float* __restrict__ xw) {
  __shared__ float xs[4][HD];
  const int blk = blockIdx.x, tid = threadIdx.x;
  const int row0 = blk * 4;
  for (int i = tid; i < 4 * HD; i += 256) xs[i >> 8][i & 255] = xin[(size_t)row0 * HD + i];
  __syncthreads();
  float acc[4][4];
#pragma unroll
  for (int g = 0; g < 4; ++g)
#pragma unroll
    for (int tt = 0; tt < 4; ++tt) acc[g][tt] = 0.f;
#pragma unroll 2
  for (int kc = 0; kc < 64; ++kc) {
#pragma unroll
    for (int g = 0; g < 4; ++g) {
      const int r = g * HD + tid;
      const float4 wv = ((const float4*)(w + (size_t)r * HD))[kc];
#pragma unroll
      for (int tt = 0; tt < 4; ++tt) {
        const float4 hv = ((const float4*)xs[tt])[kc];
        acc[g][tt] += wv.x * hv.x + wv.y * hv.y + wv.z * hv.z + wv.w * hv.w;
      }
    }
  }
#pragma unroll
  for (int g = 0; g < 4; ++g) {
    const int r = g * HD + tid;
    const float bias = ba[r] + bb[r];
#pragma unroll
    for (int tt = 0; tt < 4; ++tt)
      xw[(size_t)(row0 + tt) * 1024 + r] = acc[g][tt] + bias;
  }
}

// ---------------- shared MFMA pass: acc[m] += Wtile(Q,m) @ h ----------------
template <int Q>
__device__ __forceinline__ void mfma_pass(const short8 (&wf)[12][8],
                                          const u16* lw, const short8 (&bf)[8],
                                          int l, f32x4 (&acc)[4]) {
#pragma unroll
  for (int kk = 0; kk < 8; ++kk) {
#pragma unroll
    for (int m = 0; m < 4; ++m) {
      short8 a;
      if constexpr (Q < 3)
        a = wf[Q * 4 + m][kk];
      else
        a = *(const short8*)(lw + (size_t)m * 4096 + kk * 512 + l * 8);
      acc[m] = MFMA16(a, bf[kk], acc[m]);
    }
  }
}

__device__ __forceinline__ void epi_h(const f32x4 (&acc)[4], f32x4& cq, f32x4& h) {
#pragma unroll
  for (int r = 0; r < 4; ++r) {
    const float gi = fast_sigmoid(acc[0][r]);
    const float gf = fast_sigmoid(acc[1][r]);
    const float gg = fast_tanh(acc[2][r]);
    const float go = fast_sigmoid(acc[3][r]);
    cq[r] = gf * cq[r] + gi * gg;
    h[r] = go * fast_tanh(cq[r]);
  }
}

// ---- role 0 per-q step: z = xw + W_hh0@h0; gates; publish h0 ----
template <int Q>
__device__ __forceinline__ void l0_q(const short8 (&wf)[12][8], const u16* lw,
                                     const short8 (&bf)[8],
                                     const float* __restrict__ xwrow, int wid,
                                     int l, int G, bool active, int b, int t,
                                     u16 hb_nxt[4][264], u64* __restrict__ pt,
                                     f32x4& cq) {
  const int d0 = wid * 64 + Q * 16 + G * 4;
  f32x4 acc[4];
#pragma unroll
  for (int m = 0; m < 4; ++m) acc[m] = *(const f32x4*)(xwrow + m * 256 + d0);
  mfma_pass<Q>(wf, lw, bf, l, acc);
  if (active) {
    f32x4 h;
    epi_h(acc, cq, h);
    const u32 lo = pk2(h[0], h[1]), hi = pk2(h[2], h[3]);
    *(u32*)&hb_nxt[b][d0] = lo;
    *(u32*)&hb_nxt[b][d0 + 2] = hi;
    const u64 tg = (u64)(u32)(t + 1) << 32;
    astore(pt + (size_t)b * 128 + (d0 >> 1), (u64)lo | tg);
    astore(pt + (size_t)b * 128 + (d0 >> 1) + 1, (u64)hi | tg);
  }
}

// ---- role 1 per-q step: xw1 = bias1 + W_ih1@h0; publish tagged f32 words ----
template <int Q>
__device__ __forceinline__ void s1_q(const short8 (&wf)[12][8], const u16* lw,
                                     const short8 (&bf)[8],
                                     const float* __restrict__ bias1s, int wid,
                                     int l, int G, bool active, int b, int t,
                                     u64* __restrict__ pubX1) {
  const int d0 = wid * 64 + Q * 16 + G * 4;
  f32x4 acc[4];
#pragma unroll
  for (int m = 0; m < 4; ++m) acc[m] = *(const f32x4*)(bias1s + m * 256 + d0);
  mfma_pass<Q>(wf, lw, bf, l, acc);
  if (active) {
    const u64 tg = (u64)(u32)(t + 1) << 32;
    u64* xb = pubX1 + (size_t)t * 4096 + (size_t)b * 1024 + d0;
#pragma unroll
    for (int m = 0; m < 4; ++m)
#pragma unroll
      for (int r = 0; r < 4; ++r)
        astore(xb + m * 256 + r, (u64)__float_as_uint(acc[m][r]) | tg);
  }
}

// ---- role 2 per-q step: poll xw1, z = xw1 + W_hh1@h1; gates; write hs1 ----
template <int Q>
__device__ __forceinline__ void l2_q(const short8 (&wf)[12][8], const u16* lw,
                                     const short8 (&bf)[8],
                                     const u64* __restrict__ pubX1,
                                     float* __restrict__ hs1,
                                     u16 hb_nxt[4][264], int wid, int l, int G,
                                     bool active, int b, int t, f32x4& cq) {
  const int d0 = wid * 64 + Q * 16 + G * 4;
  f32x4 acc[4];
  if (active) {
    const u64* xb = pubX1 + (size_t)t * 4096 + (size_t)b * 1024 + d0;
    u64 v[16];
    for (;;) {
#pragma unroll
      for (int m = 0; m < 4; ++m)
#pragma unroll
        for (int r = 0; r < 4; ++r) v[m * 4 + r] = aload(xb + m * 256 + r);
      bool ok = true;
#pragma unroll
      for (int s = 0; s < 16; ++s) ok = ok && ((u32)(v[s] >> 32) == (u32)(t + 1));
      if (ok) break;
    }
#pragma unroll
    for (int m = 0; m < 4; ++m)
      acc[m] = f32x4{__uint_as_float((u32)v[m * 4 + 0]),
                     __uint_as_float((u32)v[m * 4 + 1]),
                     __uint_as_float((u32)v[m * 4 + 2]),
                     __uint_as_float((u32)v[m * 4 + 3])};
  } else {
#pragma unroll
    for (int m = 0; m < 4; ++m) acc[m] = f32x4{0.f, 0.f, 0.f, 0.f};
  }
  mfma_pass<Q>(wf, lw, bf, l, acc);
  if (active) {
    f32x4 h;
    epi_h(acc, cq, h);
    *(u32*)&hb_nxt[b][d0] = pk2(h[0], h[1]);
    *(u32*)&hb_nxt[b][d0 + 2] = pk2(h[2], h[3]);
    *(f32x4*)(hs1 + ((size_t)b * SEQ + t) * HD + d0) = h;
  }
}

// ------------------------------------------------------------- 3-CU pipeline
__global__ __launch_bounds__(256, 1) void lstm3x(
    const float* __restrict__ xw0, const u16* __restrict__ pk,
    const float* __restrict__ bias1s, float* __restrict__ hs1,
    u64* __restrict__ pubH0, u64* __restrict__ pubX1) {
  __shared__ __align__(16) u16 ldsW[16][4096];  // 128 KB: 16 weight tiles
  __shared__ __align__(16) u16 hbuf[2][4][264]; // h bf16, double-buffered

  const int role = blockIdx.x;  // 0: L0, 1: xw1 streamer, 2: L1
  const int tid = threadIdx.x;
  const int wid = tid >> 6, l = tid & 63;
  const int row16 = l & 15, G = l >> 4;
  const bool active = (row16 < 4);
  const int b = row16;
  const int beff = active ? b : 3;
  const u16* pkm = pk + (size_t)role * 262144;

  for (int i = tid; i < 2 * 4 * 264; i += 256) ((u16*)hbuf)[i] = 0;
  // LDS weight tiles: slot s <-> tile ti = (s>>2)*16 + 12 + (s&3)  (q=3 tiles)
  for (int u = tid; u < 8192; u += 256) {
    const int s = u >> 9, inner = u & 511;
    const int ti = (s >> 2) * 16 + 12 + (s & 3);
    *(short8*)&ldsW[s][inner * 8] =
        *(const short8*)(pkm + (size_t)ti * 4096 + inner * 8);
  }
  // register tiles: ti = wid*16 + 0..11 (q=0..2, all 4 gates)
  short8 wf[12][8];
#pragma unroll
  for (int i = 0; i < 12; ++i)
#pragma unroll
    for (int kk = 0; kk < 8; ++kk)
      wf[i][kk] = *(const short8*)(pkm + (size_t)(wid * 16 + i) * 4096 + kk * 512 + l * 8);
  __syncthreads();

  const u16* lw = &ldsW[wid * 4][0];

  if (role == 0) {
    f32x4 c0 = {0.f, 0.f, 0.f, 0.f}, c1 = c0, c2 = c0, c3 = c0;
    for (int t = 0; t < SEQ; ++t) {
      const int cur = t & 1, nxt = cur ^ 1;
      const u16* hrow = &hbuf[cur][beff][0];
      short8 bf[8];
#pragma unroll
      for (int kk = 0; kk < 8; ++kk) bf[kk] = *(const short8*)(hrow + kk * 32 + G * 8);
      const float* xwrow = xw0 + ((size_t)beff * SEQ + t) * 1024;
      u64* pt = pubH0 + (size_t)t * 512;
      l0_q<0>(wf, lw, bf, xwrow, wid, l, G, active, b, t, hbuf[nxt], pt, c0);
      l0_q<1>(wf, lw, bf, xwrow, wid, l, G, active, b, t, hbuf[nxt], pt, c1);
      l0_q<2>(wf, lw, bf, xwrow, wid, l, G, active, b, t, hbuf[nxt], pt, c2);
      l0_q<3>(wf, lw, bf, xwrow, wid, l, G, active, b, t, hbuf[nxt], pt, c3);
      __syncthreads();
    }
  } else if (role == 1) {
    for (int t = 0; t < SEQ; ++t) {
      const int cur = t & 1;
      {  // stage h0(t): 2 tagged words per thread
        const u64* base = pubH0 + (size_t)t * 512 + (size_t)tid * 2;
        u64 v0, v1;
        for (;;) {
          v0 = aload(base);
          v1 = aload(base + 1);
          if ((u32)(v0 >> 32) == (u32)(t + 1) && (u32)(v1 >> 32) == (u32)(t + 1)) break;
        }
        const int w = tid * 2, bi = w >> 7, dp = w & 127;
        *(u32*)&hbuf[cur][bi][dp * 2] = (u32)v0;
        *(u32*)&hbuf[cur][bi][dp * 2 + 2] = (u32)v1;
      }
      __syncthreads();
      const u16* hrow = &hbuf[cur][beff][0];
      short8 bf[8];
#pragma unroll
      for (int kk = 0; kk < 8; ++kk) bf[kk] = *(const short8*)(hrow + kk * 32 + G * 8);
      s1_q<0>(wf, lw, bf, bias1s, wid, l, G, active, b, t, pubX1);
      s1_q<1>(wf, lw, bf, bias1s, wid, l, G, active, b, t, pubX1);
      s1_q<2>(wf, lw, bf, bias1s, wid, l, G, active, b, t, pubX1);
      s1_q<3>(wf, lw, bf, bias1s, wid, l, G, active, b, t, pubX1);
    }
  } else {
    f32x4 c0 = {0.f, 0.f, 0.f, 0.f}, c1 = c0, c2 = c0, c3 = c0;
    for (int t = 0; t < SEQ; ++t) {
      const int cur = t & 1, nxt = cur ^ 1;
      const u16* hrow = &hbuf[cur][beff][0];
      short8 bf[8];
#pragma unroll
      for (int kk = 0; kk < 8; ++kk) bf[kk] = *(const short8*)(hrow + kk * 32 + G * 8);
      l2_q<0>(wf, lw, bf, pubX1, hs1, hbuf[nxt], wid, l, G, active, b, t, c0);
      l2_q<1>(wf, lw, bf, pubX1, hs1, hbuf[nxt], wid, l, G, active, b, t, c1);
      l2_q<2>(wf, lw, bf, pubX1, hs1, hbuf[nxt], wid, l, G, active, b, t, c2);
      l2_q<3>(wf, lw, bf, pubX1, hs1, hbuf[nxt], wid, l, G, active, b, t, c3);
      __syncthreads();
    }
  }
}

// ------------------------------------------------- head: stats = h @ w_lin^T + b
__global__ __launch_bounds__(256) void head_stats(
    const float* __restrict__ hs1, const float* __restrict__ wlin,
    const float* __restrict__ blin, float* __restrict__ mu_out,
    float* __restrict__ sd_out) {
  __shared__ float hsm[4][HD];
  const int blk = blockIdx.x, tid = threadIdx.x;
  const int row0 = blk * 4;
  for (int i = tid; i < 4 * HD; i += 256) hsm[i >> 8][i & 255] = hs1[(size_t)row0 * HD + i];
  __syncthreads();
  const float4* wsd = (const float4*)(wlin + (size_t)tid * HD);
  const float4* wmu = (const float4*)(wlin + (size_t)(HD + tid) * HD);
  float asd[4] = {0, 0, 0, 0}, amu[4] = {0, 0, 0, 0};
#pragma unroll 4
  for (int kc = 0; kc < 64; ++kc) {
    const float4 ws = wsd[kc], wm = wmu[kc];
#pragma unroll
    for (int tt = 0; tt < 4; ++tt) {
      const float4 hv = ((const float4*)hsm[tt])[kc];
      asd[tt] += ws.x * hv.x + ws.y * hv.y + ws.z * hv.z + ws.w * hv.w;
      amu[tt] += wm.x * hv.x + wm.y * hv.y + wm.z * hv.z + wm.w * hv.w;
    }
  }
  const float bsd = blin[tid], bmu = blin[HD + tid];
#pragma unroll
  for (int tt = 0; tt < 4; ++tt) {
    const float zs = asd[tt] + bsd;
    const float sp = (zs > 15.f) ? zs : __logf(1.f + __expf(zs));  // softplus
    sd_out[(size_t)(row0 + tt) * HD + tid] = sp;
    mu_out[(size_t)(row0 + tt) * HD + tid] = amu[tt] + bmu;
  }
}

// ---------------------------------- finalize: std_full + sample
__global__ __launch_bounds__(256) void finalize_fill(
    const float* __restrict__ eps, float* __restrict__ out) {
  float* sample = out;        // currently holds softplus(std) temp
  float* mu = out + 524288;
  float* sf = out + 1048576;  // [2048][256][256]
  const int row = blockIdx.x;
  const int tid = threadIdx.x;
  __shared__ float sd[HD];
  sd[tid] = sample[(size_t)row * HD + tid];
  __syncthreads();
  float4* dst = (float4*)(sf + (size_t)row * HD * HD);
  const int rr = tid >> 6, m = tid & 63;
#pragma unroll 4
  for (int g = 0; g < 64; ++g) {
    const int r = g * 4 + rr;
    float4 v = make_float4(0.f, 0.f, 0.f, 0.f);
    const int base = m * 4;
    if (r >= base && r < base + 4) ((float*)&v)[r - base] = sd[r];
    dst[(size_t)r * 64 + m] = v;
  }
  const float mu_v = mu[(size_t)row * HD + tid];
  const float e = eps[(size_t)row * HD + tid];
  sample[(size_t)row * HD + tid] = mu_v + sqrtf(sd[tid]) * e;
}

extern "C" void kernel_launch(void* const* d_in, const int* in_sizes, int n_in,
                              void* d_out, int out_size, void* d_ws, size_t ws_size,
                              hipStream_t stream) {
  const float* x     = (const float*)d_in[0];
  const float* eps   = (const float*)d_in[1];
  const float* w_ih0 = (const float*)d_in[2];
  const float* w_hh0 = (const float*)d_in[3];
  const float* b_ih0 = (const float*)d_in[4];
  const float* b_hh0 = (const float*)d_in[5];
  const float* w_ih1 = (const float*)d_in[6];
  const float* w_hh1 = (const float*)d_in[7];
  const float* b_ih1 = (const float*)d_in[8];
  const float* b_hh1 = (const float*)d_in[9];
  const float* w_lin = (const float*)d_in[10];
  const float* b_lin = (const float*)d_in[11];
  float* out = (float*)d_out;

  // Scratch carved from std_full output region (fully rewritten by finalize
  // each call -> tags never stale at launch; replay-safe).
  float* scratch = out + 1048576;
  float* xw0    = scratch;                      // 2,097,152 f32
  float* hs1    = scratch + 2097152;            //   524,288 f32
  u16*   pkW    = (u16*)(scratch + 2621440);    //   786,432 u16
  float* bias1s = scratch + 3014656;            //     1,024 f32
  u64*   pubH0  = (u64*)(scratch + 3015936);    //   262,144 u64 (2 MB)
  u64*   pubX1  = (u64*)(scratch + 3540224);    // 2,097,152 u64 (16 MB)

  hipLaunchKernelGGL(prep_pack, dim3(3076), dim3(256), 0, stream,
                     w_hh0, w_ih1, w_hh1, b_ih1, b_hh1, pkW, bias1s);
  hipLaunchKernelGGL(xw_gemm, dim3(512), dim3(256), 0, stream,
                     x, w_ih0, b_ih0, b_hh0, xw0);
  hipLaunchKernelGGL(lstm3x, dim3(3), dim3(256), 0, stream,
                     xw0, pkW, bias1s, hs1, pubH0, pubX1);
  hipLaunchKernelGGL(head_stats, dim3(512), dim3(256), 0, stream, hs1, w_lin, b_lin,
                     out + 524288, out);
  hipLaunchKernelGGL(finalize_fill, dim3(2048), dim3(256), 0, stream, eps, out);
}

// Round 8
// 3787.898 us; speedup vs baseline: 1.3983x; 1.3983x over previous
//
#include <hip/hip_runtime.h>
#include <hip/hip_bf16.h>

// GaussianLSTM: x(4,512,256) -> 2-layer LSTM(H=256) -> Gaussian head.
// Outputs concat: sample (524288) | mu (524288) | std_full (134217728) f32.
//
// Round 8: 3-CU pipeline, 8-wave WGs, spill-free full weight residency.
//   Per CU: 8 waves x 6 reg tiles (192 VGPR) + 16 LDS tiles (128 KB)
//   = entire 512 KB matrix resident. 2 waves/SIMD (256 VGPR budget).
//   WG0 (L0): W_hh0; recurrence via LDS hbuf + 1 barrier/step; publishes h0
//     as tagged u64 words (agent atomics; payload|tag same word).
//   WG1 (streamer): W_ih1; polls h0 (off-chain), publishes xw1 tagged words.
//   WG2 (L1): W_hh1; consumes xw1 + own recurrence; writes hs1.
//   xw0 packed bf16, prefetched 1 step ahead (L2-cold otherwise).
//   Replay-safe: pubs in std_full region (finalize rewrites every call; f32
//   bit patterns / 0xAA never equal tags 1..512). Deadlock-free DAG.

#define HD 256
#define SEQ 512

typedef __attribute__((ext_vector_type(8))) short short8;
typedef __attribute__((ext_vector_type(4))) float f32x4;
using u16 = unsigned short;
using u32 = unsigned int;
using u64 = unsigned long long;

#define MFMA16(a, bm, c) __builtin_amdgcn_mfma_f32_16x16x32_bf16((a), (bm), (c), 0, 0, 0)

__device__ inline u16 f2bf(float x) {
  u32 u = __float_as_uint(x);
  u32 r = (u + 0x7FFFu + ((u >> 16) & 1u)) >> 16;
  return (u16)r;
}
__device__ inline u32 pk2(float a, float b) {
  return (u32)f2bf(a) | ((u32)f2bf(b) << 16);
}
__device__ inline float fast_sigmoid(float z) { return 1.0f / (1.0f + __expf(-z)); }
__device__ inline float fast_tanh(float z) { return 1.0f - 2.0f / (1.0f + __expf(2.0f * z)); }

__device__ __forceinline__ u64 aload(const u64* p) {
  return __hip_atomic_load(p, __ATOMIC_RELAXED, __HIP_MEMORY_SCOPE_AGENT);
}
__device__ __forceinline__ void astore(u64* p, u64 v) {
  __hip_atomic_store(p, v, __ATOMIC_RELAXED, __HIP_MEMORY_SCOPE_AGENT);
}

__device__ __forceinline__ f32x4 unpack4(uint2 p) {
  return f32x4{__uint_as_float(p.x << 16), __uint_as_float(p.x & 0xFFFF0000u),
               __uint_as_float(p.y << 16), __uint_as_float(p.y & 0xFFFF0000u)};
}

__device__ __forceinline__ void epi_h(const f32x4 (&acc)[4], f32x4& cq, f32x4& h) {
#pragma unroll
  for (int r = 0; r < 4; ++r) {
    const float gi = fast_sigmoid(acc[0][r]);
    const float gf = fast_sigmoid(acc[1][r]);
    const float gg = fast_tanh(acc[2][r]);
    const float go = fast_sigmoid(acc[3][r]);
    cq[r] = gf * cq[r] + gi * gg;
    h[r] = go * fast_tanh(cq[r]);
  }
}

// ---------------- prep: pack W_hh0/W_ih1/W_hh1 into bf16 MFMA-frag layout ----
// pk[mat][ti][kk][ll][j]: ti = dg*4 + m (dg 0..15, m 0..3);
// row = m*256 + dg*16 + (ll&15); k = kk*32 + (ll>>4)*8 + j.
__global__ __launch_bounds__(256) void prep_pack2(
    const float* __restrict__ whh0, const float* __restrict__ wih1,
    const float* __restrict__ whh1, const float* __restrict__ bi1,
    const float* __restrict__ bh1, u16* __restrict__ pk,
    float* __restrict__ bias1s) {
  const int idx = blockIdx.x * 256 + threadIdx.x;
  if (idx < 786432) {
    const int mat = idx >> 18;
    const int e = idx & 262143;
    const int ti = e >> 12, r2 = e & 4095;
    const int kk = r2 >> 9, ll = (r2 >> 3) & 63, j = r2 & 7;
    const int dg = ti >> 2, m = ti & 3;
    const int row = m * 256 + dg * 16 + (ll & 15);
    const int k = kk * 32 + (ll >> 4) * 8 + j;
    const float* src = (mat == 0) ? whh0 : (mat == 1) ? wih1 : whh1;
    pk[idx] = f2bf(src[(size_t)row * 256 + k]);
  } else {
    const int i = idx - 786432;
    if (i < 1024) bias1s[i] = bi1[i] + bh1[i];
  }
}

// --------------------- xw0 = x @ w_ih0^T + biases, packed bf16 ----------------
__global__ __launch_bounds__(256) void xw_gemm_bf(
    const float* __restrict__ xin, const float* __restrict__ w,
    const float* __restrict__ ba, const float* __restrict__ bb,
    u16* __restrict__ xwp) {
  __shared__ float xs[4][HD];
  const int blk = blockIdx.x, tid = threadIdx.x;
  const int row0 = blk * 4;
  for (int i = tid; i < 4 * HD; i += 256) xs[i >> 8][i & 255] = xin[(size_t)row0 * HD + i];
  __syncthreads();
  float acc[4][4];
#pragma unroll
  for (int g = 0; g < 4; ++g)
#pragma unroll
    for (int tt = 0; tt < 4; ++tt) acc[g][tt] = 0.f;
#pragma unroll 2
  for (int kc = 0; kc < 64; ++kc) {
#pragma unroll
    for (int g = 0; g < 4; ++g) {
      const int r = g * HD + tid;
      const float4 wv = ((const float4*)(w + (size_t)r * HD))[kc];
#pragma unroll
      for (int tt = 0; tt < 4; ++tt) {
        const float4 hv = ((const float4*)xs[tt])[kc];
        acc[g][tt] += wv.x * hv.x + wv.y * hv.y + wv.z * hv.z + wv.w * hv.w;
      }
    }
  }
#pragma unroll
  for (int g = 0; g < 4; ++g) {
    const int r = g * HD + tid;
    const float bias = ba[r] + bb[r];
#pragma unroll
    for (int tt = 0; tt < 4; ++tt)
      xwp[(size_t)(row0 + tt) * 1024 + r] = f2bf(acc[g][tt] + bias);
  }
}

// ------------------------------------------------------------- 3-CU LSTM
__global__ __launch_bounds__(512, 2) void lstm8w(
    const u16* __restrict__ xwp, const u16* __restrict__ pk,
    const float* __restrict__ bias1s, float* __restrict__ hs1,
    u64* __restrict__ pubH0, u64* __restrict__ pubX1) {
  __shared__ __align__(16) u16 ldsW[16][4096];   // 128 KB: 16 weight tiles
  __shared__ __align__(16) u16 hbuf[2][4][264];  // h bf16, ping-pong

  const int role = blockIdx.x;  // 0: L0, 1: streamer, 2: L1
  const int tid = threadIdx.x;
  const int w = tid >> 6, l = tid & 63;
  const int r16 = l & 15, G = l >> 4;
  const bool active = (r16 < 4);
  const int b = r16;
  const int beff = active ? b : 3;
  const int dgA = 2 * w, dgB = 2 * w + 1;
  const u16* pkm = pk + (size_t)role * 262144;

  for (int i = tid; i < 2112; i += 512) ((u16*)hbuf)[i] = 0;
  // LDS tiles: slot s -> wave s>>1, dg = 2*(s>>1)+1, m = 2+(s&1)
  for (int u = tid; u < 8192; u += 512) {
    const int s = u >> 9, inner = u & 511;
    const int ti = (2 * (s >> 1) + 1) * 4 + 2 + (s & 1);
    *(short8*)&ldsW[s][inner * 8] = *(const short8*)(pkm + (size_t)ti * 4096 + inner * 8);
  }
  // register tiles: dgA gates 0..3, dgB gates 0..1  (192 VGPR)
  short8 wf[6][8];
#pragma unroll
  for (int i = 0; i < 4; ++i)
#pragma unroll
    for (int kk = 0; kk < 8; ++kk)
      wf[i][kk] = *(const short8*)(pkm + ((size_t)(dgA * 4 + i) * 8 + kk) * 512 + l * 8);
#pragma unroll
  for (int i = 0; i < 2; ++i)
#pragma unroll
    for (int kk = 0; kk < 8; ++kk)
      wf[4 + i][kk] = *(const short8*)(pkm + ((size_t)(dgB * 4 + i) * 8 + kk) * 512 + l * 8);
  const u16* lw0 = &ldsW[2 * w][0];
  const u16* lw1 = &ldsW[2 * w + 1][0];
  __syncthreads();

  if (role == 0) {
    // ------------- layer 0 -------------
    f32x4 cA = {0.f, 0.f, 0.f, 0.f}, cB = cA;
    uint2 xnA[4], xnB[4];
    if (active) {
#pragma unroll
      for (int m = 0; m < 4; ++m) {
        xnA[m] = *(const uint2*)(xwp + (size_t)b * SEQ * 1024 + m * 256 + dgA * 16 + G * 4);
        xnB[m] = *(const uint2*)(xwp + (size_t)b * SEQ * 1024 + m * 256 + dgB * 16 + G * 4);
      }
    }
    for (int t = 0; t < SEQ; ++t) {
      const int cur = t & 1, nxt = cur ^ 1;
      const u16* hr = &hbuf[cur][beff][0];
      const int tn = (t + 1 < SEQ) ? t + 1 : t;
      const u64 tg = (u64)(u32)(t + 1) << 32;
      // ---- phase A (dgA): all-register tiles
      f32x4 aA[4];
#pragma unroll
      for (int m = 0; m < 4; ++m) aA[m] = active ? unpack4(xnA[m]) : f32x4{0.f, 0.f, 0.f, 0.f};
      if (active) {
#pragma unroll
        for (int m = 0; m < 4; ++m)
          xnA[m] = *(const uint2*)(xwp + ((size_t)b * SEQ + tn) * 1024 + m * 256 + dgA * 16 + G * 4);
      }
#pragma unroll
      for (int kk = 0; kk < 8; ++kk) {
        const short8 bk = *(const short8*)(hr + kk * 32 + G * 8);
        aA[0] = MFMA16(wf[0][kk], bk, aA[0]);
        aA[1] = MFMA16(wf[1][kk], bk, aA[1]);
        aA[2] = MFMA16(wf[2][kk], bk, aA[2]);
        aA[3] = MFMA16(wf[3][kk], bk, aA[3]);
      }
      if (active) {
        f32x4 h;
        epi_h(aA, cA, h);
        const u32 lo = pk2(h[0], h[1]), hi = pk2(h[2], h[3]);
        *(u32*)&hbuf[nxt][b][dgA * 16 + G * 4] = lo;
        *(u32*)&hbuf[nxt][b][dgA * 16 + G * 4 + 2] = hi;
        const size_t wi = (size_t)t * 512 + b * 128 + dgA * 8 + G * 2;
        astore(pubH0 + wi, (u64)lo | tg);
        astore(pubH0 + wi + 1, (u64)hi | tg);
      }
      // ---- phase B (dgB): 2 reg + 2 LDS tiles
      f32x4 aB[4];
#pragma unroll
      for (int m = 0; m < 4; ++m) aB[m] = active ? unpack4(xnB[m]) : f32x4{0.f, 0.f, 0.f, 0.f};
      if (active) {
#pragma unroll
        for (int m = 0; m < 4; ++m)
          xnB[m] = *(const uint2*)(xwp + ((size_t)b * SEQ + tn) * 1024 + m * 256 + dgB * 16 + G * 4);
      }
#pragma unroll
      for (int kk = 0; kk < 8; ++kk) {
        const short8 bk = *(const short8*)(hr + kk * 32 + G * 8);
        aB[0] = MFMA16(wf[4][kk], bk, aB[0]);
        aB[1] = MFMA16(wf[5][kk], bk, aB[1]);
        aB[2] = MFMA16(*(const short8*)(lw0 + kk * 512 + l * 8), bk, aB[2]);
        aB[3] = MFMA16(*(const short8*)(lw1 + kk * 512 + l * 8), bk, aB[3]);
      }
      if (active) {
        f32x4 h;
        epi_h(aB, cB, h);
        const u32 lo = pk2(h[0], h[1]), hi = pk2(h[2], h[3]);
        *(u32*)&hbuf[nxt][b][dgB * 16 + G * 4] = lo;
        *(u32*)&hbuf[nxt][b][dgB * 16 + G * 4 + 2] = hi;
        const size_t wi = (size_t)t * 512 + b * 128 + dgB * 8 + G * 2;
        astore(pubH0 + wi, (u64)lo | tg);
        astore(pubH0 + wi + 1, (u64)hi | tg);
      }
      __syncthreads();
    }
  } else if (role == 1) {
    // ------------- xw1 streamer -------------
    for (int t = 0; t < SEQ; ++t) {
      const int cur = t & 1;
      {  // stage h0(t): 1 tagged word per thread
        const u64* bp = pubH0 + (size_t)t * 512 + tid;
        u64 v = aload(bp);
        while ((u32)(v >> 32) != (u32)(t + 1)) v = aload(bp);
        *(u32*)&hbuf[cur][tid >> 7][(tid & 127) * 2] = (u32)v;
      }
      __syncthreads();
      const u16* hr = &hbuf[cur][beff][0];
      const u64 tg = (u64)(u32)(t + 1) << 32;
      // ---- phase A
      f32x4 aA[4];
#pragma unroll
      for (int m = 0; m < 4; ++m)
        aA[m] = active ? *(const f32x4*)(bias1s + m * 256 + dgA * 16 + G * 4)
                       : f32x4{0.f, 0.f, 0.f, 0.f};
#pragma unroll
      for (int kk = 0; kk < 8; ++kk) {
        const short8 bk = *(const short8*)(hr + kk * 32 + G * 8);
        aA[0] = MFMA16(wf[0][kk], bk, aA[0]);
        aA[1] = MFMA16(wf[1][kk], bk, aA[1]);
        aA[2] = MFMA16(wf[2][kk], bk, aA[2]);
        aA[3] = MFMA16(wf[3][kk], bk, aA[3]);
      }
      if (active) {
        u64* xb = pubX1 + (size_t)t * 4096 + (size_t)b * 1024 + dgA * 16 + G * 4;
#pragma unroll
        for (int m = 0; m < 4; ++m)
#pragma unroll
          for (int r = 0; r < 4; ++r)
            astore(xb + m * 256 + r, (u64)__float_as_uint(aA[m][r]) | tg);
      }
      // ---- phase B
      f32x4 aB[4];
#pragma unroll
      for (int m = 0; m < 4; ++m)
        aB[m] = active ? *(const f32x4*)(bias1s + m * 256 + dgB * 16 + G * 4)
                       : f32x4{0.f, 0.f, 0.f, 0.f};
#pragma unroll
      for (int kk = 0; kk < 8; ++kk) {
        const short8 bk = *(const short8*)(hr + kk * 32 + G * 8);
        aB[0] = MFMA16(wf[4][kk], bk, aB[0]);
        aB[1] = MFMA16(wf[5][kk], bk, aB[1]);
        aB[2] = MFMA16(*(const short8*)(lw0 + kk * 512 + l * 8), bk, aB[2]);
        aB[3] = MFMA16(*(const short8*)(lw1 + kk * 512 + l * 8), bk, aB[3]);
      }
      if (active) {
        u64* xb = pubX1 + (size_t)t * 4096 + (size_t)b * 1024 + dgB * 16 + G * 4;
#pragma unroll
        for (int m = 0; m < 4; ++m)
#pragma unroll
          for (int r = 0; r < 4; ++r)
            astore(xb + m * 256 + r, (u64)__float_as_uint(aB[m][r]) | tg);
      }
    }
  } else {
    // ------------- layer 1 -------------
    f32x4 cA = {0.f, 0.f, 0.f, 0.f}, cB = cA;
    for (int t = 0; t < SEQ; ++t) {
      const int cur = t & 1, nxt = cur ^ 1;
      const u16* hr = &hbuf[cur][beff][0];
      // ---- phase A: poll xw1(dgA), then MFMA
      f32x4 aA[4];
      if (active) {
        const u64* xb = pubX1 + (size_t)t * 4096 + (size_t)b * 1024 + dgA * 16 + G * 4;
        u64 v[16];
        for (;;) {
#pragma unroll
          for (int m = 0; m < 4; ++m)
#pragma unroll
            for (int r = 0; r < 4; ++r) v[m * 4 + r] = aload(xb + m * 256 + r);
          bool ok = true;
#pragma unroll
          for (int s = 0; s < 16; ++s) ok = ok && ((u32)(v[s] >> 32) == (u32)(t + 1));
          if (__all(ok)) break;
        }
#pragma unroll
        for (int m = 0; m < 4; ++m)
          aA[m] = f32x4{__uint_as_float((u32)v[m * 4 + 0]), __uint_as_float((u32)v[m * 4 + 1]),
                        __uint_as_float((u32)v[m * 4 + 2]), __uint_as_float((u32)v[m * 4 + 3])};
      } else {
#pragma unroll
        for (int m = 0; m < 4; ++m) aA[m] = f32x4{0.f, 0.f, 0.f, 0.f};
      }
#pragma unroll
      for (int kk = 0; kk < 8; ++kk) {
        const short8 bk = *(const short8*)(hr + kk * 32 + G * 8);
        aA[0] = MFMA16(wf[0][kk], bk, aA[0]);
        aA[1] = MFMA16(wf[1][kk], bk, aA[1]);
        aA[2] = MFMA16(wf[2][kk], bk, aA[2]);
        aA[3] = MFMA16(wf[3][kk], bk, aA[3]);
      }
      if (active) {
        f32x4 h;
        epi_h(aA, cA, h);
        *(u32*)&hbuf[nxt][b][dgA * 16 + G * 4] = pk2(h[0], h[1]);
        *(u32*)&hbuf[nxt][b][dgA * 16 + G * 4 + 2] = pk2(h[2], h[3]);
        *(f32x4*)(hs1 + ((size_t)b * SEQ + t) * HD + dgA * 16 + G * 4) = h;
      }
      // ---- phase B
      f32x4 aB[4];
      if (active) {
        const u64* xb = pubX1 + (size_t)t * 4096 + (size_t)b * 1024 + dgB * 16 + G * 4;
        u64 v[16];
        for (;;) {
#pragma unroll
          for (int m = 0; m < 4; ++m)
#pragma unroll
            for (int r = 0; r < 4; ++r) v[m * 4 + r] = aload(xb + m * 256 + r);
          bool ok = true;
#pragma unroll
          for (int s = 0; s < 16; ++s) ok = ok && ((u32)(v[s] >> 32) == (u32)(t + 1));
          if (__all(ok)) break;
        }
#pragma unroll
        for (int m = 0; m < 4; ++m)
          aB[m] = f32x4{__uint_as_float((u32)v[m * 4 + 0]), __uint_as_float((u32)v[m * 4 + 1]),
                        __uint_as_float((u32)v[m * 4 + 2]), __uint_as_float((u32)v[m * 4 + 3])};
      } else {
#pragma unroll
        for (int m = 0; m < 4; ++m) aB[m] = f32x4{0.f, 0.f, 0.f, 0.f};
      }
#pragma unroll
      for (int kk = 0; kk < 8; ++kk) {
        const short8 bk = *(const short8*)(hr + kk * 32 + G * 8);
        aB[0] = MFMA16(wf[4][kk], bk, aB[0]);
        aB[1] = MFMA16(wf[5][kk], bk, aB[1]);
        aB[2] = MFMA16(*(const short8*)(lw0 + kk * 512 + l * 8), bk, aB[2]);
        aB[3] = MFMA16(*(const short8*)(lw1 + kk * 512 + l * 8), bk, aB[3]);
      }
      if (active) {
        f32x4 h;
        epi_h(aB, cB, h);
        *(u32*)&hbuf[nxt][b][dgB * 16 + G * 4] = pk2(h[0], h[1]);
        *(u32*)&hbuf[nxt][b][dgB * 16 + G * 4 + 2] = pk2(h[2], h[3]);
        *(f32x4*)(hs1 + ((size_t)b * SEQ + t) * HD + dgB * 16 + G * 4) = h;
      }
      __syncthreads();
    }
  }
}

// ------------------------------------------------- head: stats = h @ w_lin^T + b
__global__ __launch_bounds__(256) void head_stats(
    const float* __restrict__ hs1, const float* __restrict__ wlin,
    const float* __restrict__ blin, float* __restrict__ mu_out,
    float* __restrict__ sd_out) {
  __shared__ float hsm[4][HD];
  const int blk = blockIdx.x, tid = threadIdx.x;
  const int row0 = blk * 4;
  for (int i = tid; i < 4 * HD; i += 256) hsm[i >> 8][i & 255] = hs1[(size_t)row0 * HD + i];
  __syncthreads();
  const float4* wsd = (const float4*)(wlin + (size_t)tid * HD);
  const float4* wmu = (const float4*)(wlin + (size_t)(HD + tid) * HD);
  float asd[4] = {0, 0, 0, 0}, amu[4] = {0, 0, 0, 0};
#pragma unroll 4
  for (int kc = 0; kc < 64; ++kc) {
    const float4 ws = wsd[kc], wm = wmu[kc];
#pragma unroll
    for (int tt = 0; tt < 4; ++tt) {
      const float4 hv = ((const float4*)hsm[tt])[kc];
      asd[tt] += ws.x * hv.x + ws.y * hv.y + ws.z * hv.z + ws.w * hv.w;
      amu[tt] += wm.x * hv.x + wm.y * hv.y + wm.z * hv.z + wm.w * hv.w;
    }
  }
  const float bsd = blin[tid], bmu = blin[HD + tid];
#pragma unroll
  for (int tt = 0; tt < 4; ++tt) {
    const float zs = asd[tt] + bsd;
    const float sp = (zs > 15.f) ? zs : __logf(1.f + __expf(zs));  // softplus
    sd_out[(size_t)(row0 + tt) * HD + tid] = sp;
    mu_out[(size_t)(row0 + tt) * HD + tid] = amu[tt] + bmu;
  }
}

// ---------------------------------- finalize: std_full + sample
__global__ __launch_bounds__(256) void finalize_fill(
    const float* __restrict__ eps, float* __restrict__ out) {
  float* sample = out;        // currently holds softplus(std) temp
  float* mu = out + 524288;
  float* sf = out + 1048576;  // [2048][256][256]
  const int row = blockIdx.x;
  const int tid = threadIdx.x;
  __shared__ float sd[HD];
  sd[tid] = sample[(size_t)row * HD + tid];
  __syncthreads();
  float4* dst = (float4*)(sf + (size_t)row * HD * HD);
  const int rr = tid >> 6, m = tid & 63;
#pragma unroll 4
  for (int g = 0; g < 64; ++g) {
    const int r = g * 4 + rr;
    float4 v = make_float4(0.f, 0.f, 0.f, 0.f);
    const int base = m * 4;
    if (r >= base && r < base + 4) ((float*)&v)[r - base] = sd[r];
    dst[(size_t)r * 64 + m] = v;
  }
  const float mu_v = mu[(size_t)row * HD + tid];
  const float e = eps[(size_t)row * HD + tid];
  sample[(size_t)row * HD + tid] = mu_v + sqrtf(sd[tid]) * e;
}

extern "C" void kernel_launch(void* const* d_in, const int* in_sizes, int n_in,
                              void* d_out, int out_size, void* d_ws, size_t ws_size,
                              hipStream_t stream) {
  const float* x     = (const float*)d_in[0];
  const float* eps   = (const float*)d_in[1];
  const float* w_ih0 = (const float*)d_in[2];
  const float* w_hh0 = (const float*)d_in[3];
  const float* b_ih0 = (const float*)d_in[4];
  const float* b_hh0 = (const float*)d_in[5];
  const float* w_ih1 = (const float*)d_in[6];
  const float* w_hh1 = (const float*)d_in[7];
  const float* b_ih1 = (const float*)d_in[8];
  const float* b_hh1 = (const float*)d_in[9];
  const float* w_lin = (const float*)d_in[10];
  const float* b_lin = (const float*)d_in[11];
  float* out = (float*)d_out;

  // Scratch carved from std_full output region (fully rewritten by finalize
  // each call -> tags never stale at launch; replay-safe).
  float* scratch = out + 1048576;
  u16*   xwp    = (u16*)scratch;                // 2,097,152 u16 (4 MB)
  float* hs1    = scratch + 1048576;            //   524,288 f32
  u16*   pkW    = (u16*)(scratch + 1572864);    //   786,432 u16
  float* bias1s = scratch + 1966080;            //     1,024 f32
  u64*   pubH0  = (u64*)(scratch + 1967104);    //   262,144 u64 (2 MB)
  u64*   pubX1  = (u64*)(scratch + 2491392);    // 2,097,152 u64 (16 MB)

  hipLaunchKernelGGL(prep_pack2, dim3(3076), dim3(256), 0, stream,
                     w_hh0, w_ih1, w_hh1, b_ih1, b_hh1, pkW, bias1s);
  hipLaunchKernelGGL(xw_gemm_bf, dim3(512), dim3(256), 0, stream,
                     x, w_ih0, b_ih0, b_hh0, xwp);
  hipLaunchKernelGGL(lstm8w, dim3(3), dim3(512), 0, stream,
                     xwp, pkW, bias1s, hs1, pubH0, pubX1);
  hipLaunchKernelGGL(head_stats, dim3(512), dim3(256), 0, stream, hs1, w_lin, b_lin,
                     out + 524288, out);
  hipLaunchKernelGGL(finalize_fill, dim3(2048), dim3(256), 0, stream, eps, out);
}